// Round 6
// baseline (7249.454 us; speedup 1.0000x reference)
//
#include <hip/hip_runtime.h>
#include <stdint.h>

// LSTM N=32, T=2048, D=H=512. Persistent kernel, 8 groups x 32 WGs (grid=256=#CUs,
// co-resident). Each WG owns 16 hidden units (64 gate rows); weights stationary in
// VGPR MFMA A-fragments, rows ordered unit*4+gate. x and h split hi/lo bf16
// (two MFMA chains) for ~f32 accuracy.
//
// R9: software-pipelined GEMM-ahead. Key insight: the x-projection is
// recurrence-independent AND producer lane == consumer lane for
// xh[t][batch][unit][gates] -> xh never leaves the CU (lives in LDS).
// Structure: 64-step blocks; while the recurrence runs block b, each step also
// advances the x-GEMM of block b+1 by one timestep into the other LDS xh buffer.
// The GEMM work fills the h-exchange wait window; the recurrence epilogue reads
// its 4 gate pre-activations with one ds_read_b128. This deletes the xpk pack
// prologue + group barrier + 256MB of MALL traffic (x read once as f32, packed
// inline during staging).
// h exchange: R8's proven tagged fire-and-forget protocol verbatim. Each h elem
// is {packed hi|lo bf16, tag=t+1} stored atomically via global_store_dwordx2
// sc0 sc1 (MALL); consumers speculatively load 4x dwordx4 and poll tags == t.
// All cross-WG traffic stays sc0 sc1 (R5/R6 proved sc0-only unreliable).

#define T_STEPS 2048
#define HD 512
#define NBATCH 32
#define XSROW 516   // u32 row stride: 516 % 32 == 4 -> conflict-free-ish swizzle
#define BLK 64      // pipeline block: xh LDS double-buffer of 64 timesteps

typedef __attribute__((ext_vector_type(8))) short short8;
typedef __attribute__((ext_vector_type(4))) float f32x4;
typedef __attribute__((ext_vector_type(4))) uint u32x4;
typedef __attribute__((ext_vector_type(2))) uint u32x2;

static __device__ __forceinline__ uint bf_rne(float f) {
    uint u = __builtin_bit_cast(uint, f);
    return (u + 0x7FFFu + ((u >> 16) & 1u)) >> 16;
}
static __device__ __forceinline__ float bf_f(uint h) {
    return __builtin_bit_cast(float, h << 16);
}
// f32 -> (bf16_hi<<16) | bf16_lo
static __device__ __forceinline__ uint packsplit(float f) {
    uint hi = bf_rne(f);
    uint lo = bf_rne(f - bf_f(hi));
    return (hi << 16) | lo;
}

// Build hi/lo B-fragments (8 bf16 each) from 8 packed u32 (consecutive k).
static __device__ __forceinline__ void buildfrag(const uint* p, short8& bh, short8& bl) {
    uint4 w0 = *(const uint4*)p;
    uint4 w1 = *(const uint4*)(p + 4);
    uint4 hi, lo;
    hi.x = __builtin_amdgcn_perm(w0.y, w0.x, 0x07060302u);
    hi.y = __builtin_amdgcn_perm(w0.w, w0.z, 0x07060302u);
    hi.z = __builtin_amdgcn_perm(w1.y, w1.x, 0x07060302u);
    hi.w = __builtin_amdgcn_perm(w1.w, w1.z, 0x07060302u);
    lo.x = __builtin_amdgcn_perm(w0.y, w0.x, 0x05040100u);
    lo.y = __builtin_amdgcn_perm(w0.w, w0.z, 0x05040100u);
    lo.z = __builtin_amdgcn_perm(w1.y, w1.x, 0x05040100u);
    lo.w = __builtin_amdgcn_perm(w1.w, w1.z, 0x05040100u);
    bh = __builtin_bit_cast(short8, hi);
    bl = __builtin_bit_cast(short8, lo);
}

static __device__ __forceinline__ float sigf(float v) { return 1.f / (1.f + __expf(-v)); }
static __device__ __forceinline__ float tanhfast(float v) { return 2.f / (1.f + __expf(-2.f * v)) - 1.f; }

// ---- MALL-coherent (device-scope) ops: sc0 sc1 bypass L1/L2 ----
static __device__ __forceinline__ void st_mall2(uint* p, u32x2 v) {
    asm volatile("global_store_dwordx2 %0, %1, off sc0 sc1" :: "v"(p), "v"(v) : "memory");
}
// issue four 16B tagged loads (no wait) — results unread until wait_tied4
static __device__ __forceinline__ void ld_mall_issue4(const uint* p0, const uint* p1,
                                                      const uint* p2, const uint* p3,
                                                      u32x4& a, u32x4& b, u32x4& c, u32x4& d) {
    asm volatile("global_load_dwordx4 %0, %4, off sc0 sc1\n\t"
                 "global_load_dwordx4 %1, %5, off sc0 sc1\n\t"
                 "global_load_dwordx4 %2, %6, off sc0 sc1\n\t"
                 "global_load_dwordx4 %3, %7, off sc0 sc1"
                 : "=&v"(a), "=&v"(b), "=&v"(c), "=&v"(d)
                 : "v"(p0), "v"(p1), "v"(p2), "v"(p3) : "memory");
}
static __device__ __forceinline__ void wait_tied4(u32x4& a, u32x4& b, u32x4& c, u32x4& d) {
    asm volatile("s_waitcnt vmcnt(0)" : "+v"(a), "+v"(b), "+v"(c), "+v"(d) :: "memory");
}

__global__ __launch_bounds__(256, 1) void lstm_pers(
    const float* __restrict__ x, const float* __restrict__ Wih,
    const float* __restrict__ bih, const float* __restrict__ Whh,
    const float* __restrict__ bhh, float* __restrict__ y,
    uint* __restrict__ hq)
{
    __shared__ uint  xsh[2][4 * XSROW];      // x staging double-buffer (16512 B)
    __shared__ uint  hs[4 * XSROW];          // h staging (8256 B)
    __shared__ float xhl[2][BLK * 256];      // xh pipeline: 2 blocks x 64 t x 1KB (131072 B)

    const int b   = blockIdx.x;
    const int g   = b & 7;
    const int w   = b >> 3;
    const int tid = threadIdx.x;
    const int wv  = tid >> 6;
    const int l   = tid & 63;
    const int q   = l >> 4;
    const int m   = l & 15;

    // ---- stationary weight A-fragments: rows ordered unit*4+gate ----
    const int gateA = m & 3, ulA = m >> 2;
    const int Arow  = gateA * HD + ((w << 4) + (wv << 2) + ulA);
    short8 wf[32];
#pragma unroll
    for (int kt = 0; kt < 32; ++kt) {
        const int k0 = kt * 32 + q * 8;
        const float* src = (k0 < HD) ? (Wih + (size_t)Arow * HD + k0)
                                     : (Whh + (size_t)Arow * HD + (k0 - HD));
        float4 a  = ((const float4*)src)[0];
        float4 c4 = ((const float4*)src)[1];
        uint4 uu;
        uu.x = bf_rne(a.x)  | (bf_rne(a.y)  << 16);
        uu.y = bf_rne(a.z)  | (bf_rne(a.w)  << 16);
        uu.z = bf_rne(c4.x) | (bf_rne(c4.y) << 16);
        uu.w = bf_rne(c4.z) | (bf_rne(c4.w) << 16);
        wf[kt] = __builtin_bit_cast(short8, uu);
    }

    const int unitC = (w << 4) + (wv << 2) + q;
    float bias_[4];
#pragma unroll
    for (int i = 0; i < 4; ++i) bias_[i] = bih[i * HD + unitC] + bhh[i * HD + unitC];

    const bool act = (m < 4);
    const int  ul  = (wv << 2) + q;          // unit-local index 0..15 (xh addressing)

    int budget = 1 << 21;                    // global spin budget: guarantees termination

    // stage one batch row (row wv) of x(s) into xsh[s&1]; inline f32 -> hi|lo pack
    auto stage_x = [&](int s) {
        if (s >= T_STEPS) return;
        const float* xp = x + ((size_t)(g * 4 + wv) * T_STEPS + s) * HD;
        uint* dst = &xsh[s & 1][wv * XSROW];
#pragma unroll
        for (int j2 = 0; j2 < 2; ++j2) {
            const int k0 = j2 * 256 + l * 4;
            float4 t4 = *(const float4*)(xp + k0);
            u32x4 u;
            u.x = packsplit(t4.x); u.y = packsplit(t4.y);
            u.z = packsplit(t4.z); u.w = packsplit(t4.w);
            *(u32x4*)&dst[k0] = u;
        }
    };

    const f32x4 zero4 = {0.f, 0.f, 0.f, 0.f};

    // ---- prologue: x-GEMM for block 0 into xhl[0] ----
    stage_x(0);
    __syncthreads();
    for (int s = 0; s < BLK; ++s) {
        f32x4 c0 = zero4, c1 = zero4, c2 = zero4, c3 = zero4;
#pragma unroll
        for (int kt = 0; kt < 16; ++kt) {
            short8 bh, bl;
            buildfrag(&xsh[s & 1][(l & 3) * XSROW + kt * 32 + q * 8], bh, bl);
            if (kt & 1) {
                c1 = __builtin_amdgcn_mfma_f32_16x16x32_bf16(wf[kt], bh, c1, 0, 0, 0);
                c3 = __builtin_amdgcn_mfma_f32_16x16x32_bf16(wf[kt], bl, c3, 0, 0, 0);
            } else {
                c0 = __builtin_amdgcn_mfma_f32_16x16x32_bf16(wf[kt], bh, c0, 0, 0, 0);
                c2 = __builtin_amdgcn_mfma_f32_16x16x32_bf16(wf[kt], bl, c2, 0, 0, 0);
            }
        }
        if (act) {
            f32x4 sum = c0 + c1 + c2 + c3;
            *(f32x4*)&xhl[0][(s << 8) + (m << 6) + (ul << 2)] = sum;
        }
        stage_x(s + 1);
        __syncthreads();
    }

    float cst = 0.f;

    // ---- fused main loop: recurrence step t + x-GEMM step t+BLK ----
    for (int t = 0; t < T_STEPS; ++t) {
        const int tg = t + BLK;
        u32x4 va, vb, vc, vd;

        // tagged h row for this wave's batch: 512 pairs = 1024 dwords
        uint* const hp = hq + (size_t)(((t - 1) & 1) * NBATCH + g * 4 + wv) * (HD * 2);
        if (t > 0) {
            // speculative issue (no wait) — latency hidden under the GEMM slot
            ld_mall_issue4(hp + 4 * l, hp + 256 + 4 * l, hp + 512 + 4 * l,
                           hp + 768 + 4 * l, va, vb, vc, vd);
        }

        // GEMM-ahead slot: x-projection of step tg into the other xh buffer
        if (tg < T_STEPS) {
            f32x4 c0 = zero4, c1 = zero4, c2 = zero4, c3 = zero4;
#pragma unroll
            for (int kt = 0; kt < 16; ++kt) {
                short8 bh, bl;
                buildfrag(&xsh[tg & 1][(l & 3) * XSROW + kt * 32 + q * 8], bh, bl);
                if (kt & 1) {
                    c1 = __builtin_amdgcn_mfma_f32_16x16x32_bf16(wf[kt], bh, c1, 0, 0, 0);
                    c3 = __builtin_amdgcn_mfma_f32_16x16x32_bf16(wf[kt], bl, c3, 0, 0, 0);
                } else {
                    c0 = __builtin_amdgcn_mfma_f32_16x16x32_bf16(wf[kt], bh, c0, 0, 0, 0);
                    c2 = __builtin_amdgcn_mfma_f32_16x16x32_bf16(wf[kt], bl, c2, 0, 0, 0);
                }
            }
            if (act) {
                f32x4 sum = c0 + c1 + c2 + c3;
                *(f32x4*)&xhl[(tg >> 6) & 1][((tg & 63) << 8) + (m << 6) + (ul << 2)] = sum;
            }
            stage_x(tg + 1);
        }

        f32x4 h0 = zero4, h1 = zero4, h2 = zero4, h3 = zero4;
        if (t > 0) {
            // data-poll: all 8 tags (4 loads x 2 pairs) must equal t
            wait_tied4(va, vb, vc, vd);
            const uint want = (uint)t;
            for (;;) {
                int ok = (va.y == want) & (va.w == want) & (vb.y == want) & (vb.w == want)
                       & (vc.y == want) & (vc.w == want) & (vd.y == want) & (vd.w == want);
                if (__all(ok)) break;
                if (--budget <= 0) break;
                ld_mall_issue4(hp + 4 * l, hp + 256 + 4 * l, hp + 512 + 4 * l,
                               hp + 768 + 4 * l, va, vb, vc, vd);
                wait_tied4(va, vb, vc, vd);
            }
            // strip tags -> hs (lane covers units {2l,2l+1} of each 128-unit block)
            *(u32x2*)&hs[wv * XSROW + 2 * l]       = (u32x2){va.x, va.z};
            *(u32x2*)&hs[wv * XSROW + 128 + 2 * l] = (u32x2){vb.x, vb.z};
            *(u32x2*)&hs[wv * XSROW + 256 + 2 * l] = (u32x2){vc.x, vc.z};
            *(u32x2*)&hs[wv * XSROW + 384 + 2 * l] = (u32x2){vd.x, vd.z};
        }
        __syncthreads();   // hs ready; xsh[tg&1] reads done before next stage_x

        if (t > 0) {
#pragma unroll
            for (int kt = 0; kt < 16; ++kt) {
                short8 bh, bl;
                buildfrag(&hs[(l & 3) * XSROW + kt * 32 + q * 8], bh, bl);
                if (kt & 1) {
                    h1 = __builtin_amdgcn_mfma_f32_16x16x32_bf16(wf[16 + kt], bh, h1, 0, 0, 0);
                    h3 = __builtin_amdgcn_mfma_f32_16x16x32_bf16(wf[16 + kt], bl, h3, 0, 0, 0);
                } else {
                    h0 = __builtin_amdgcn_mfma_f32_16x16x32_bf16(wf[16 + kt], bh, h0, 0, 0, 0);
                    h2 = __builtin_amdgcn_mfma_f32_16x16x32_bf16(wf[16 + kt], bl, h2, 0, 0, 0);
                }
            }
        }

        if (act) {
            const f32x4 xh4 = *(const f32x4*)
                &xhl[(t >> 6) & 1][((t & 63) << 8) + (m << 6) + (ul << 2)];
            const float v0 = xh4.x + h0.x + h1.x + h2.x + h3.x + bias_[0];   // i
            const float v1 = xh4.y + h0.y + h1.y + h2.y + h3.y + bias_[1];   // f
            const float v2 = xh4.z + h0.z + h1.z + h2.z + h3.z + bias_[2];   // o
            const float v3 = xh4.w + h0.w + h1.w + h2.w + h3.w + bias_[3];   // g
            const float ig = sigf(v0), fg = sigf(v1), og = sigf(v2), gg = tanhfast(v3);
            cst = fg * cst + ig * gg;
            const float hv = og * tanhfast(cst);

            // direct tagged publish: ONE atomic 8B store, fire-and-forget
            const uint p  = packsplit(hv);
            const int  bi = g * 4 + m;
            uint* dst = hq + (size_t)((t & 1) * NBATCH + bi) * (HD * 2) + unitC * 2;
            st_mall2(dst, (u32x2){p, (uint)t + 1u});
            y[((size_t)bi * T_STEPS + t) * HD + unitC] =
                __builtin_bit_cast(float, p & 0xFFFF0000u)
              + __builtin_bit_cast(float, p << 16);
        }

        __syncthreads();   // hs reads done before next strip; xsh staged before reads
    }
}

extern "C" void kernel_launch(void* const* d_in, const int* in_sizes, int n_in,
                              void* d_out, int out_size, void* d_ws, size_t ws_size,
                              hipStream_t stream) {
    (void)in_sizes; (void)n_in; (void)out_size; (void)ws_size;
    const float* x   = (const float*)d_in[0];
    const float* Wih = (const float*)d_in[1];
    const float* bih = (const float*)d_in[2];
    const float* Whh = (const float*)d_in[3];
    const float* bhh = (const float*)d_in[4];
    float* y = (float*)d_out;

    // workspace: tagged hbuf only (2 slots x 32 x 512 x 8B = 256K)
    uint* hq = (uint*)d_ws;
    // zero tags every launch (stale tags must never read as fresh)
    hipMemsetAsync(hq, 0, 262144, stream);
    lstm_pers<<<dim3(256), dim3(256), 0, stream>>>(x, Wih, bih, Whh, bhh, y, hq);
}